// Round 2
// baseline (222.608 us; speedup 1.0000x reference)
//
#include <hip/hip_runtime.h>
#include <hip/hip_fp16.h>

typedef _Float16 half_t;
typedef __attribute__((ext_vector_type(2))) _Float16 f16x2;
typedef __attribute__((ext_vector_type(8))) _Float16 f16x8;
typedef __attribute__((ext_vector_type(4))) float f32x4;

// ---------------------------------------------------------------------------
// Separable MLP: h = relu(z[src].W1a + z[dst].W1b + b1) ; out = h.W2 + b2
// R2: REVERT edge kernel to R0 (3-deep pipeline, plain loads — R1's 4-deep +
//   nontemporal regressed: 73.3->79.7 us, hbm_gbps DOWN, FETCH +7MB. Edge is
//   contention-bound, not outstanding-request-starved). INSTRUMENT: edge is
//   launched as 4 quarter-range dispatches (~19 us each) so that gemm/prep
//   surface in rocprof top-5 (bar drops 73 -> ~20 us). Accounting says
//   prep+gemm+overhead = 140 us but roofline says ~35 us -> must localize
//   the hidden ~100 us before touching gemm.
// Phase 0 (prep): blocks [0,128): W1 -> f16 B-fragment blob (64 KB);
//   blocks [128,..): z fp32 -> zh f16. (Separate prep beats fused cvt:
//   R12's in-gemm cvt spilled ~44 MB. Separate beats skipping zh: R6-R8.)
// Phase 1 (gemm_uv): Y[node] = [zh@W1a | zh@W1b], 256-thr blocks, grid 512,
//   M=16/wave, A-prefetch 1 group ahead, W1 via global_load_lds.
//   (R11 U/V-split, R12 fused-cvt, R13 512-thr block all regressed vs this.)
// Phase 2 (edge_decode): out[e] = b2 + relu(Y[s][0:128]+Y[d][128:256]+b1).W2
//   16 lanes/edge, 2048 blocks (8/CU), 3-deep pipeline: gathers 2 iters
//   ahead, indices 3 ahead. Fabric-bound at ~239 MB HBM-miss / 73 us.
// Y column permute: position j in each 128-half holds hidden index
//   n(j) = (j&7)*16 + (j>>3); b1/W2 permuted identically in phase 2.
// ---------------------------------------------------------------------------

// B-fragment (ks in 0..3, nt in 0..15): lane L elem j holds
//   B[k = ks*32 + (L>>4)*8 + j][ncol = nt*16 + (L&15)]
// where B[k][ncol] = W1[(ncol<128 ? k : 128+k)][ncol & 127].
// Flat f16 index t = ((ks*16 + nt)*64 + L)*8 + j.
__global__ void prep_kernel(const float* __restrict__ z,
                            const float* __restrict__ W1,
                            half_t* __restrict__ zh,
                            half_t* __restrict__ w1s, int n8) {
    if (blockIdx.x < 128) {
        const int t = blockIdx.x * 256 + threadIdx.x;   // 0..32767
        const int j  = t & 7;
        const int L  = (t >> 3) & 63;
        const int nt = (t >> 9) & 15;
        const int ks = t >> 13;
        const int k    = ks * 32 + (L >> 4) * 8 + j;
        const int ncol = nt * 16 + (L & 15);
        const int row  = (ncol < 128) ? k : 128 + k;
        w1s[t] = (half_t)W1[row * 128 + (ncol & 127)];
    } else {
        const int t = (blockIdx.x - 128) * 256 + threadIdx.x;
        if (t < n8) {
            const float4 a = reinterpret_cast<const float4*>(z)[2 * t];
            const float4 b = reinterpret_cast<const float4*>(z)[2 * t + 1];
            f16x8 o;
            o[0] = (_Float16)a.x; o[1] = (_Float16)a.y;
            o[2] = (_Float16)a.z; o[3] = (_Float16)a.w;
            o[4] = (_Float16)b.x; o[5] = (_Float16)b.y;
            o[6] = (_Float16)b.z; o[7] = (_Float16)b.w;
            reinterpret_cast<f16x8*>(zh)[t] = o;
        }
    }
}

__global__ __launch_bounds__(256, 2)
void gemm_uv_kernel(const half_t* __restrict__ zh,
                    const half_t* __restrict__ w1s,
                    half_t* __restrict__ Y,
                    int n_groups, int stride_groups) {
    __shared__ __align__(16) half_t w1_lds[32768];   // 64 KB
    const int wave = threadIdx.x >> 6;
    const int lane = threadIdx.x & 63;

    // Stage 64 KB via global_load_lds: LDS dest = uniform base + lane*16,
    // exactly the flat fragment layout. Conflict-free (R7 verified).
#pragma unroll
    for (int rnd = 0; rnd < 16; ++rnd) {
        const int chunk = rnd * 4 + wave;       // 0..63, wave-uniform
        const char* gp = (const char*)w1s + chunk * 1024 + lane * 16;
        __builtin_amdgcn_global_load_lds(
            (const __attribute__((address_space(1))) void*)gp,
            (__attribute__((address_space(3))) void*)
                ((char*)w1_lds + chunk * 1024),
            16, 0, 0);
    }
    __syncthreads();

    const int nlo  = lane & 15;
    const int quad = lane >> 4;
    const f16x8* blds = reinterpret_cast<const f16x8*>(w1_lds);

    int g = blockIdx.x * 4 + wave;
    if (g >= n_groups) return;

    // N_NODES = 16 * n_groups exactly -> no bounds guards anywhere.
    const half_t* arow = zh + ((size_t)(g * 16 + nlo) * 128) + quad * 8;
    f16x8 av[4];
#pragma unroll
    for (int ks = 0; ks < 4; ++ks)
        av[ks] = *reinterpret_cast<const f16x8*>(arow + ks * 32);

    for (; g < n_groups; g += stride_groups) {
        const int gn = g + stride_groups;
        const int gpi = (gn < n_groups) ? gn : g;  // harmless re-read on last
        const half_t* arow_n = zh + ((size_t)(gpi * 16 + nlo) * 128) + quad * 8;
        f16x8 avn[4];
#pragma unroll
        for (int ks = 0; ks < 4; ++ks)
            avn[ks] = *reinterpret_cast<const f16x8*>(arow_n + ks * 32);

        f32x4 acc[16];
#pragma unroll
        for (int nt = 0; nt < 16; ++nt) acc[nt] = (f32x4){0.f, 0.f, 0.f, 0.f};

#pragma unroll
        for (int ks = 0; ks < 4; ++ks) {
            const f16x8* bp = blds + ks * 1024 + lane;
#pragma unroll
            for (int nt = 0; nt < 16; ++nt)
                acc[nt] = __builtin_amdgcn_mfma_f32_16x16x32_f16(
                    av[ks], bp[nt * 64], acc[nt], 0, 0, 0);
        }

        // C/D: row m = quad*4 + r, col = nt*16 + nlo.
#pragma unroll
        for (int r = 0; r < 4; ++r) {
            const int nr = g * 16 + quad * 4 + r;
            f16x8 up, vp;
#pragma unroll
            for (int t = 0; t < 8; ++t) {
                up[t] = (_Float16)acc[t][r];
                vp[t] = (_Float16)acc[8 + t][r];
            }
            *reinterpret_cast<f16x8*>(Y + (size_t)nr * 256 + nlo * 8) = up;
            *reinterpret_cast<f16x8*>(Y + (size_t)nr * 256 + 128 + nlo * 8) = vp;
        }

#pragma unroll
        for (int ks = 0; ks < 4; ++ks) av[ks] = avn[ks];
    }
}

static __device__ __forceinline__ f16x2 pair2(const f16x8& v, int p) {
    f16x2 r; r[0] = v[2 * p]; r[1] = v[2 * p + 1]; return r;
}

// Edge phase: 16 lanes per edge (4 edges/wave/iter), coalesced 256-B segment
// gathers. Three-deep pipeline: gathers issued 2 iters ahead, indices 3.
// R2: range-based (es/ed/out pre-offset by caller) so the launch can be
// split into quarters for rocprof visibility. Body = R0 verbatim otherwise.
__global__ __launch_bounds__(256, 8)
void edge_decode_kernel(const half_t* __restrict__ Y,
                        const int* __restrict__ es,
                        const int* __restrict__ ed,
                        const float* __restrict__ b1,
                        const float* __restrict__ W2,
                        const float* __restrict__ b2,
                        float* __restrict__ out,
                        int n_e, int stride_e) {
    __shared__ __align__(16) half_t b1h[128];
    __shared__ __align__(16) half_t w2h[128];
    if (threadIdx.x < 128) {
        const int i = threadIdx.x;
        const int n = (i & 7) * 16 + (i >> 3);   // match Y's column permute
        b1h[i] = (half_t)b1[n];
        w2h[i] = (half_t)W2[n];
    }
    __syncthreads();

    const int lane  = threadIdx.x & 63;
    const int sl    = lane & 15;    // 16-B slice within the 256-B half-row
    const int eslot = lane >> 4;    // which of the wave's 4 edges
    const f16x8 bv = reinterpret_cast<const f16x8*>(b1h)[sl];
    const f16x8 wv = reinterpret_cast<const f16x8*>(w2h)[sl];
    const float b2v = b2[0];
    const f16x2 zero2 = {(_Float16)0, (_Float16)0};

    const int w = blockIdx.x * 4 + (threadIdx.x >> 6);
    int e0 = w * 4;
    if (e0 >= n_e) return;

    // iter-0 gathers
    int ec = e0 + eslot; if (ec >= n_e) ec = 0;
    int sa = es[ec], da = ed[ec];
    f16x8 u0 = *reinterpret_cast<const f16x8*>(Y + (size_t)sa * 256 + sl * 8);
    f16x8 v0 = *reinterpret_cast<const f16x8*>(Y + (size_t)da * 256 + 128 +
                                               sl * 8);
    // iter-1 gathers
    ec = e0 + stride_e + eslot; if (ec >= n_e) ec = 0;
    sa = es[ec]; da = ed[ec];
    f16x8 u1 = *reinterpret_cast<const f16x8*>(Y + (size_t)sa * 256 + sl * 8);
    f16x8 v1 = *reinterpret_cast<const f16x8*>(Y + (size_t)da * 256 + 128 +
                                               sl * 8);
    // iter-2 indices
    ec = e0 + 2 * stride_e + eslot; if (ec >= n_e) ec = 0;
    int s2 = es[ec], d2 = ed[ec];

    for (; e0 < n_e; e0 += stride_e) {
        const int e = e0 + eslot;
        const bool valid = (e < n_e);

        // issue iter+2 gathers (consumed two iterations from now)
        const f16x8 u2 = *reinterpret_cast<const f16x8*>(
            Y + (size_t)s2 * 256 + sl * 8);
        const f16x8 v2 = *reinterpret_cast<const f16x8*>(
            Y + (size_t)d2 * 256 + 128 + sl * 8);

        // fetch indices three iterations ahead
        {
            int en = e0 + 3 * stride_e + eslot;
            if (en >= n_e) en = 0;
            s2 = es[en];
            d2 = ed[en];
        }

        float acc = 0.f;
#pragma unroll
        for (int p = 0; p < 4; ++p) {
            f16x2 h2 = pair2(u0, p) + pair2(v0, p) + pair2(bv, p);
            h2 = __builtin_elementwise_max(h2, zero2);
            acc = __builtin_amdgcn_fdot2(h2, pair2(wv, p), acc, false);
        }
        acc += __shfl_xor(acc, 1);
        acc += __shfl_xor(acc, 2);
        acc += __shfl_xor(acc, 4);
        acc += __shfl_xor(acc, 8);
        if (sl == 0 && valid) out[e] = acc + b2v;

        u0 = u1; v0 = v1;
        u1 = u2; v1 = v2;
    }
}

// Insurance fallback (only if workspace is unexpectedly tiny): correct, slow.
__global__ void naive_edge_kernel(const float* __restrict__ z,
                                  const int* __restrict__ eidx,
                                  const float* __restrict__ W1,
                                  const float* __restrict__ b1,
                                  const float* __restrict__ W2,
                                  const float* __restrict__ b2,
                                  float* __restrict__ out, int n_edges) {
    __shared__ float feat[256];
    __shared__ float red[2];
    const int e = blockIdx.x;
    const int t = threadIdx.x;           // 128 threads
    const int s = eidx[e], d = eidx[n_edges + e];
    feat[t] = z[(size_t)s * 128 + t];
    feat[128 + t] = z[(size_t)d * 128 + t];
    __syncthreads();
    float h = b1[t];
    for (int k = 0; k < 256; ++k) h = fmaf(feat[k], W1[k * 128 + t], h);
    float p = fmaxf(h, 0.f) * W2[t];
    for (int off = 32; off; off >>= 1) p += __shfl_down(p, off);
    if ((t & 63) == 0) red[t >> 6] = p;
    __syncthreads();
    if (t == 0) out[e] = red[0] + red[1] + b2[0];
}

extern "C" void kernel_launch(void* const* d_in, const int* in_sizes, int n_in,
                              void* d_out, int out_size, void* d_ws,
                              size_t ws_size, hipStream_t stream) {
    const float* z   = (const float*)d_in[0];
    const int* eidx  = (const int*)d_in[1];   // int64 ref passed as int32
    const float* W1  = (const float*)d_in[2];
    const float* b1  = (const float*)d_in[3];
    const float* W2  = (const float*)d_in[4];
    const float* b2  = (const float*)d_in[5];
    float* out       = (float*)d_out;

    const int nz      = in_sizes[0];          // 12,800,000
    const int n_nodes = nz / 128;             // 100,000
    const int n_edges = in_sizes[1] / 2;      // 1,000,000

    const size_t Y_bytes   = (size_t)n_nodes * 256 * sizeof(half_t); // 51.2 MB
    const size_t zh_bytes  = (size_t)nz * sizeof(half_t);            // 25.6 MB
    const size_t w1s_bytes = 32768 * sizeof(half_t);                 // 64 KB

    if (ws_size >= Y_bytes + zh_bytes + w1s_bytes) {
        half_t* Y   = (half_t*)d_ws;
        half_t* zh  = (half_t*)((char*)d_ws + Y_bytes);
        half_t* w1s = (half_t*)((char*)d_ws + Y_bytes + zh_bytes);

        const int n8 = nz / 8;                      // 1.6M f16x8 chunks
        const int zblocks = (n8 + 255) / 256;       // 6250
        prep_kernel<<<128 + zblocks, 256, 0, stream>>>(z, W1, zh, w1s, n8);

        const int n_groups = n_nodes / 16;          // 6250 exact
        const int gblocks  = 512;                   // 2 blocks/CU residency
        gemm_uv_kernel<<<gblocks, 256, 0, stream>>>(zh, w1s, Y, n_groups,
                                                    gblocks * 4);

        // Edge phase in 4 quarter-range dispatches (instrumentation: puts
        // each edge row at ~19 us so gemm/prep can surface in top-5).
        const int eblocks  = 2048;                  // 8 blocks/CU -> 32 w/CU
        const int stride_e = eblocks * 4 * 4;       // 32768
        const int nq = 4;
        int qbase = 0;
        for (int q = 0; q < nq; ++q) {
            const int qlen = n_edges / nq + (q < (n_edges % nq) ? 1 : 0);
            edge_decode_kernel<<<eblocks, 256, 0, stream>>>(
                Y, eidx + qbase, eidx + n_edges + qbase, b1, W2, b2,
                out + qbase, qlen, stride_e);
            qbase += qlen;
        }
    } else {
        naive_edge_kernel<<<n_edges, 128, 0, stream>>>(z, eidx, W1, b1, W2, b2,
                                                       out, n_edges);
    }
}

// Round 3
// 195.613 us; speedup vs baseline: 1.1380x; 1.1380x over previous
//
#include <hip/hip_runtime.h>
#include <hip/hip_fp16.h>

typedef _Float16 half_t;
typedef __attribute__((ext_vector_type(2))) _Float16 f16x2;
typedef __attribute__((ext_vector_type(4))) _Float16 f16x4;
typedef __attribute__((ext_vector_type(8))) _Float16 f16x8;
typedef __attribute__((ext_vector_type(4))) float f32x4;

// ---------------------------------------------------------------------------
// Separable MLP: h = relu(z[src].W1a + z[dst].W1b + b1) ; out = h.W2 + b2
// R3: gemm rework. R2 counters showed gemm_uv = 48.5 us with NOTHING
//   saturated (Mfma 4.7%, VALU 2.7%, occ 16.7%, hbm 47%) -> latency-bound at
//   2 waves/SIMD (64KB LDS capped residency) with serial ds_read->MFMA chain.
//   New: REGISTER-B gemm. W1 blob (64KB) is time-invariant; each of 4 waves
//   holds a quarter (64 VGPR) permanently. No LDS, no syncs, no ds_read, no
//   per-block re-staging (-32MB FETCH). launch_bounds(256,3) -> ~12 waves/CU.
//   Y store granularity f16x8 -> f16x4 (4 tiles/wave) => NEW column permute
//   n(i) = ((i>>6)*4 + (i&3))*16 + ((i>>2)&15), applied per 128-half;
//   edge b1/W2 permute updated to match (edge is otherwise positional).
// Phase 0 (prep): blocks [0,128): W1 -> f16 B-fragment blob (64 KB);
//   blocks [128,..): z fp32 -> zh f16.
// Phase 2 (edge_decode): out[e] = b2 + relu(Y[s][0:128]+Y[d][128:256]+b1).W2
//   16 lanes/edge, 2048 blocks, 3-deep pipeline (R0 config — R1's 4-deep+nt
//   regressed). Kept as 4 quarter-dispatches for rocprof visibility (~6-8 us
//   tax; remove once gemm is settled).
// ---------------------------------------------------------------------------

// B-fragment (ks in 0..3, nt in 0..15): lane L elem j holds
//   B[k = ks*32 + (L>>4)*8 + j][ncol = nt*16 + (L&15)]
// where B[k][ncol] = W1[(ncol<128 ? k : 128+k)][ncol & 127].
// Flat f16 index t = ((ks*16 + nt)*64 + L)*8 + j.
__global__ void prep_kernel(const float* __restrict__ z,
                            const float* __restrict__ W1,
                            half_t* __restrict__ zh,
                            half_t* __restrict__ w1s, int n8) {
    if (blockIdx.x < 128) {
        const int t = blockIdx.x * 256 + threadIdx.x;   // 0..32767
        const int j  = t & 7;
        const int L  = (t >> 3) & 63;
        const int nt = (t >> 9) & 15;
        const int ks = t >> 13;
        const int k    = ks * 32 + (L >> 4) * 8 + j;
        const int ncol = nt * 16 + (L & 15);
        const int row  = (ncol < 128) ? k : 128 + k;
        w1s[t] = (half_t)W1[row * 128 + (ncol & 127)];
    } else {
        const int t = (blockIdx.x - 128) * 256 + threadIdx.x;
        if (t < n8) {
            const float4 a = reinterpret_cast<const float4*>(z)[2 * t];
            const float4 b = reinterpret_cast<const float4*>(z)[2 * t + 1];
            f16x8 o;
            o[0] = (_Float16)a.x; o[1] = (_Float16)a.y;
            o[2] = (_Float16)a.z; o[3] = (_Float16)a.w;
            o[4] = (_Float16)b.x; o[5] = (_Float16)b.y;
            o[6] = (_Float16)b.z; o[7] = (_Float16)b.w;
            reinterpret_cast<f16x8*>(zh)[t] = o;
        }
    }
}

// Register-B gemm: block = 4 waves, each wave wq owns nt-tiles
// [wq*4, wq*4+4) (64 output cols) held in 64 VGPRs. All 4 waves walk the
// same group sequence (A-loads dedup in L1/L2). One group per block-iter.
// Per wave per group: 4 A-loads (f16x8) + 16 MFMA + 4 f16x4 stores.
__global__ __launch_bounds__(256, 3)
void gemm_regb_kernel(const half_t* __restrict__ zh,
                      const half_t* __restrict__ w1s,
                      half_t* __restrict__ Y,
                      int n_groups, int stride_groups) {
    const int wq   = threadIdx.x >> 6;   // wave's column-quarter, 0..3
    const int lane = threadIdx.x & 63;
    const int nlo  = lane & 15;
    const int quad = lane >> 4;

    // Load this wave's quarter of the B blob into registers (16 KB/wave,
    // L2-resident after the first block touches it).
    const f16x8* blob = reinterpret_cast<const f16x8*>(w1s);
    f16x8 breg[4][4];                    // [ks][ntp]
#pragma unroll
    for (int ks = 0; ks < 4; ++ks)
#pragma unroll
        for (int ntp = 0; ntp < 4; ++ntp)
            breg[ks][ntp] = blob[(ks * 16 + wq * 4 + ntp) * 64 + lane];

    int g = blockIdx.x;
    if (g >= n_groups) return;

    // N_NODES = 16 * n_groups exactly -> no bounds guards anywhere.
    const half_t* arow = zh + ((size_t)(g * 16 + nlo) * 128) + quad * 8;
    f16x8 av[4];
#pragma unroll
    for (int ks = 0; ks < 4; ++ks)
        av[ks] = *reinterpret_cast<const f16x8*>(arow + ks * 32);

    for (; g < n_groups; g += stride_groups) {
        const int gn = g + stride_groups;
        const int gpi = (gn < n_groups) ? gn : g;  // harmless re-read on last
        const half_t* arow_n = zh + ((size_t)(gpi * 16 + nlo) * 128) + quad * 8;
        f16x8 avn[4];
#pragma unroll
        for (int ks = 0; ks < 4; ++ks)
            avn[ks] = *reinterpret_cast<const f16x8*>(arow_n + ks * 32);

        f32x4 acc[4];
#pragma unroll
        for (int ntp = 0; ntp < 4; ++ntp) acc[ntp] = (f32x4){0.f, 0.f, 0.f, 0.f};

#pragma unroll
        for (int ks = 0; ks < 4; ++ks)
#pragma unroll
            for (int ntp = 0; ntp < 4; ++ntp)
                acc[ntp] = __builtin_amdgcn_mfma_f32_16x16x32_f16(
                    av[ks], breg[ks][ntp], acc[ntp], 0, 0, 0);

        // C/D: row m = quad*4 + r, col = (wq*4+ntp)*16 + nlo.
        // Store f16x4 {acc[0][r]..acc[3][r]} at position wq*64 + nlo*4:
        // flat position p (per 128-half) holds hidden index
        //   n(p) = ((p>>6)*4 + (p&3))*16 + ((p>>2)&15).
#pragma unroll
        for (int r = 0; r < 4; ++r) {
            const int nr = g * 16 + quad * 4 + r;
            f16x4 o;
#pragma unroll
            for (int j = 0; j < 4; ++j) o[j] = (_Float16)acc[j][r];
            *reinterpret_cast<f16x4*>(Y + (size_t)nr * 256 + wq * 64 +
                                      nlo * 4) = o;
        }

#pragma unroll
        for (int ks = 0; ks < 4; ++ks) av[ks] = avn[ks];
    }
}

static __device__ __forceinline__ f16x2 pair2(const f16x8& v, int p) {
    f16x2 r; r[0] = v[2 * p]; r[1] = v[2 * p + 1]; return r;
}

// Edge phase: 16 lanes per edge (4 edges/wave/iter), coalesced 256-B segment
// gathers. Three-deep pipeline: gathers issued 2 iters ahead, indices 3.
// Range-based (es/ed/out pre-offset by caller) for quarter-split visibility.
__global__ __launch_bounds__(256, 8)
void edge_decode_kernel(const half_t* __restrict__ Y,
                        const int* __restrict__ es,
                        const int* __restrict__ ed,
                        const float* __restrict__ b1,
                        const float* __restrict__ W2,
                        const float* __restrict__ b2,
                        float* __restrict__ out,
                        int n_e, int stride_e) {
    __shared__ __align__(16) half_t b1h[128];
    __shared__ __align__(16) half_t w2h[128];
    if (threadIdx.x < 128) {
        const int i = threadIdx.x;
        // R3 permute: position i holds hidden index
        //   n(i) = ((i>>6)*4 + (i&3))*16 + ((i>>2)&15)   (per 128-half)
        const int n = (((i >> 6) << 2) + (i & 3)) * 16 + ((i >> 2) & 15);
        b1h[i] = (half_t)b1[n];
        w2h[i] = (half_t)W2[n];
    }
    __syncthreads();

    const int lane  = threadIdx.x & 63;
    const int sl    = lane & 15;    // 16-B slice within the 256-B half-row
    const int eslot = lane >> 4;    // which of the wave's 4 edges
    const f16x8 bv = reinterpret_cast<const f16x8*>(b1h)[sl];
    const f16x8 wv = reinterpret_cast<const f16x8*>(w2h)[sl];
    const float b2v = b2[0];
    const f16x2 zero2 = {(_Float16)0, (_Float16)0};

    const int w = blockIdx.x * 4 + (threadIdx.x >> 6);
    int e0 = w * 4;
    if (e0 >= n_e) return;

    // iter-0 gathers
    int ec = e0 + eslot; if (ec >= n_e) ec = 0;
    int sa = es[ec], da = ed[ec];
    f16x8 u0 = *reinterpret_cast<const f16x8*>(Y + (size_t)sa * 256 + sl * 8);
    f16x8 v0 = *reinterpret_cast<const f16x8*>(Y + (size_t)da * 256 + 128 +
                                               sl * 8);
    // iter-1 gathers
    ec = e0 + stride_e + eslot; if (ec >= n_e) ec = 0;
    sa = es[ec]; da = ed[ec];
    f16x8 u1 = *reinterpret_cast<const f16x8*>(Y + (size_t)sa * 256 + sl * 8);
    f16x8 v1 = *reinterpret_cast<const f16x8*>(Y + (size_t)da * 256 + 128 +
                                               sl * 8);
    // iter-2 indices
    ec = e0 + 2 * stride_e + eslot; if (ec >= n_e) ec = 0;
    int s2 = es[ec], d2 = ed[ec];

    for (; e0 < n_e; e0 += stride_e) {
        const int e = e0 + eslot;
        const bool valid = (e < n_e);

        // issue iter+2 gathers (consumed two iterations from now)
        const f16x8 u2 = *reinterpret_cast<const f16x8*>(
            Y + (size_t)s2 * 256 + sl * 8);
        const f16x8 v2 = *reinterpret_cast<const f16x8*>(
            Y + (size_t)d2 * 256 + 128 + sl * 8);

        // fetch indices three iterations ahead
        {
            int en = e0 + 3 * stride_e + eslot;
            if (en >= n_e) en = 0;
            s2 = es[en];
            d2 = ed[en];
        }

        float acc = 0.f;
#pragma unroll
        for (int p = 0; p < 4; ++p) {
            f16x2 h2 = pair2(u0, p) + pair2(v0, p) + pair2(bv, p);
            h2 = __builtin_elementwise_max(h2, zero2);
            acc = __builtin_amdgcn_fdot2(h2, pair2(wv, p), acc, false);
        }
        acc += __shfl_xor(acc, 1);
        acc += __shfl_xor(acc, 2);
        acc += __shfl_xor(acc, 4);
        acc += __shfl_xor(acc, 8);
        if (sl == 0 && valid) out[e] = acc + b2v;

        u0 = u1; v0 = v1;
        u1 = u2; v1 = v2;
    }
}

// Insurance fallback (only if workspace is unexpectedly tiny): correct, slow.
__global__ void naive_edge_kernel(const float* __restrict__ z,
                                  const int* __restrict__ eidx,
                                  const float* __restrict__ W1,
                                  const float* __restrict__ b1,
                                  const float* __restrict__ W2,
                                  const float* __restrict__ b2,
                                  float* __restrict__ out, int n_edges) {
    __shared__ float feat[256];
    __shared__ float red[2];
    const int e = blockIdx.x;
    const int t = threadIdx.x;           // 128 threads
    const int s = eidx[e], d = eidx[n_edges + e];
    feat[t] = z[(size_t)s * 128 + t];
    feat[128 + t] = z[(size_t)d * 128 + t];
    __syncthreads();
    float h = b1[t];
    for (int k = 0; k < 256; ++k) h = fmaf(feat[k], W1[k * 128 + t], h);
    float p = fmaxf(h, 0.f) * W2[t];
    for (int off = 32; off; off >>= 1) p += __shfl_down(p, off);
    if ((t & 63) == 0) red[t >> 6] = p;
    __syncthreads();
    if (t == 0) out[e] = red[0] + red[1] + b2[0];
}

extern "C" void kernel_launch(void* const* d_in, const int* in_sizes, int n_in,
                              void* d_out, int out_size, void* d_ws,
                              size_t ws_size, hipStream_t stream) {
    const float* z   = (const float*)d_in[0];
    const int* eidx  = (const int*)d_in[1];   // int64 ref passed as int32
    const float* W1  = (const float*)d_in[2];
    const float* b1  = (const float*)d_in[3];
    const float* W2  = (const float*)d_in[4];
    const float* b2  = (const float*)d_in[5];
    float* out       = (float*)d_out;

    const int nz      = in_sizes[0];          // 12,800,000
    const int n_nodes = nz / 128;             // 100,000
    const int n_edges = in_sizes[1] / 2;      // 1,000,000

    const size_t Y_bytes   = (size_t)n_nodes * 256 * sizeof(half_t); // 51.2 MB
    const size_t zh_bytes  = (size_t)nz * sizeof(half_t);            // 25.6 MB
    const size_t w1s_bytes = 32768 * sizeof(half_t);                 // 64 KB

    if (ws_size >= Y_bytes + zh_bytes + w1s_bytes) {
        half_t* Y   = (half_t*)d_ws;
        half_t* zh  = (half_t*)((char*)d_ws + Y_bytes);
        half_t* w1s = (half_t*)((char*)d_ws + Y_bytes + zh_bytes);

        const int n8 = nz / 8;                      // 1.6M f16x8 chunks
        const int zblocks = (n8 + 255) / 256;       // 6250
        prep_kernel<<<128 + zblocks, 256, 0, stream>>>(z, W1, zh, w1s, n8);

        const int n_groups = n_nodes / 16;          // 6250 exact
        const int gblocks  = 1024;                  // ~3 resident/CU (VGPR)
        gemm_regb_kernel<<<gblocks, 256, 0, stream>>>(zh, w1s, Y, n_groups,
                                                      gblocks);

        // Edge phase in 4 quarter-range dispatches (instrumentation: puts
        // each edge row at ~19 us so gemm/prep can surface in top-5).
        const int eblocks  = 2048;                  // 8 blocks/CU -> 32 w/CU
        const int stride_e = eblocks * 4 * 4;       // 32768
        const int nq = 4;
        int qbase = 0;
        for (int q = 0; q < nq; ++q) {
            const int qlen = n_edges / nq + (q < (n_edges % nq) ? 1 : 0);
            edge_decode_kernel<<<eblocks, 256, 0, stream>>>(
                Y, eidx + qbase, eidx + n_edges + qbase, b1, W2, b2,
                out + qbase, qlen, stride_e);
            qbase += qlen;
        }
    } else {
        naive_edge_kernel<<<n_edges, 128, 0, stream>>>(z, eidx, W1, b1, W2, b2,
                                                       out, n_edges);
    }
}

// Round 4
// 194.660 us; speedup vs baseline: 1.1436x; 1.0049x over previous
//
#include <hip/hip_runtime.h>
#include <hip/hip_fp16.h>

typedef _Float16 half_t;
typedef __attribute__((ext_vector_type(2))) _Float16 f16x2;
typedef __attribute__((ext_vector_type(4))) _Float16 f16x4;
typedef __attribute__((ext_vector_type(8))) _Float16 f16x8;
typedef __attribute__((ext_vector_type(4))) float f32x4;

// ---------------------------------------------------------------------------
// Separable MLP: h = relu(z[src].W1a + z[dst].W1b + b1) ; out = h.W2 + b2
// R4: FUSE prep into gemm. R3's register-B gemm won (48.5 -> ~24 us inferred,
//   total 222.6 -> 195.6). Top-5 now = harness fillBuffer (41 us, fixed
//   overhead ~75 us/replay we cannot touch). Largest controllable item was
//   prep (77 MB stream, ~15 us) whose only purpose was feeding zh to gemm.
//   New gemm reads z (f32) directly and converts in-register after the
//   prefetch wait (+16 VGPR, ~145 total, no spill at 3 waves/SIMD), and
//   builds its W1 B-fragments from W1 f32 at block start (L2-served).
//   Deletes prep kernel + zh + w1s buffers: -51.2 MB net traffic, -1 launch.
//   Old session's "fused cvt spilled" verdict was against the LDS-gemm
//   structure (128 VGPR + staging) — does not apply to register-B gemm.
//   Edge quarter-split instrumentation removed (-3 launches, -~5 us).
// Phase 1 (gemm_fused): Y[node] = [z@W1a | z@W1b] in f16. Block = 4 waves;
//   wave wq owns 64 output cols (B quarter in 64 VGPRs, built from W1).
//   Per wave per group: 8 float4 A-loads (prefetched 1 group ahead),
//   16 MFMA 16x16x32_f16, 4 f16x4 stores. 768 blocks = 3/CU residency.
// Phase 2 (edge_decode): out[e] = b2 + relu(Y[s][0:128]+Y[d][128:256]+b1).W2
//   16 lanes/edge, 2048 blocks, 3-deep pipeline (R0 config; R1's 4-deep+nt
//   regressed: contention-bound, not request-starved). Single dispatch.
// Y row layout (256 f16): position p holds hidden index
//   n(p) = ((p>>6)*4 + (p&3))*16 + ((p>>2)&15) per 128-half; b1/W2 permuted
//   identically in edge (edge math is positional, so any bijection works).
// ---------------------------------------------------------------------------

// Fused A-convert + register-B gemm.
// B-fragment (nt = wq*4+ntp in 0..15): lane L elem j holds
//   B[k = ks*32 + (L>>4)*8 + j][ncol = nt*16 + (L&15)]
// where B[k][ncol] = W1[(ncol<128 ? k : 128+k)][ncol & 127].
// wq 0,1 -> U half (W1 rows [0,128)); wq 2,3 -> V half (rows [128,256)).
__global__ __launch_bounds__(256, 3)
void gemm_fused_kernel(const float* __restrict__ z,
                       const float* __restrict__ W1,
                       half_t* __restrict__ Y,
                       int n_groups, int stride_groups) {
    const int wq   = threadIdx.x >> 6;   // wave's column-quarter, 0..3
    const int lane = threadIdx.x & 63;
    const int nlo  = lane & 15;
    const int quad = lane >> 4;

    // Build this wave's B quarter from W1 (f32, L2-resident after first
    // touches). One-time cost per block (~128 scalar loads/lane).
    const int rbase = (wq >= 2) ? 128 : 0;
    f16x8 breg[4][4];                    // [ks][ntp]
#pragma unroll
    for (int ks = 0; ks < 4; ++ks)
#pragma unroll
        for (int ntp = 0; ntp < 4; ++ntp) {
            const int col  = (wq & 1) * 64 + ntp * 16 + nlo;
            const int row0 = rbase + ks * 32 + quad * 8;
            f16x8 b;
#pragma unroll
            for (int j = 0; j < 8; ++j)
                b[j] = (_Float16)W1[(row0 + j) * 128 + col];
            breg[ks][ntp] = b;
        }

    int g = blockIdx.x;
    if (g >= n_groups) return;

    // N_NODES = 16 * n_groups exactly -> no bounds guards anywhere.
    // A row for this lane: z[g*16 + nlo][quad*8 + ks*32 + 0..7] (f32).
    const float4* ap = reinterpret_cast<const float4*>(
        z + ((size_t)(g * 16 + nlo) * 128) + quad * 8);
    float4 af[4][2];
#pragma unroll
    for (int ks = 0; ks < 4; ++ks) {
        af[ks][0] = ap[ks * 8];
        af[ks][1] = ap[ks * 8 + 1];
    }
    f16x8 av[4];
#pragma unroll
    for (int ks = 0; ks < 4; ++ks) {
        f16x8 t;
        t[0] = (_Float16)af[ks][0].x; t[1] = (_Float16)af[ks][0].y;
        t[2] = (_Float16)af[ks][0].z; t[3] = (_Float16)af[ks][0].w;
        t[4] = (_Float16)af[ks][1].x; t[5] = (_Float16)af[ks][1].y;
        t[6] = (_Float16)af[ks][1].z; t[7] = (_Float16)af[ks][1].w;
        av[ks] = t;
    }

    for (; g < n_groups; g += stride_groups) {
        const int gn = g + stride_groups;
        const int gpi = (gn < n_groups) ? gn : g;  // harmless re-read on last
        const float4* apn = reinterpret_cast<const float4*>(
            z + ((size_t)(gpi * 16 + nlo) * 128) + quad * 8);
        float4 afn[4][2];
#pragma unroll
        for (int ks = 0; ks < 4; ++ks) {
            afn[ks][0] = apn[ks * 8];
            afn[ks][1] = apn[ks * 8 + 1];
        }

        f32x4 acc[4];
#pragma unroll
        for (int ntp = 0; ntp < 4; ++ntp)
            acc[ntp] = (f32x4){0.f, 0.f, 0.f, 0.f};

#pragma unroll
        for (int ks = 0; ks < 4; ++ks)
#pragma unroll
            for (int ntp = 0; ntp < 4; ++ntp)
                acc[ntp] = __builtin_amdgcn_mfma_f32_16x16x32_f16(
                    av[ks], breg[ks][ntp], acc[ntp], 0, 0, 0);

        // C/D: row m = quad*4 + r, col = (wq*4+ntp)*16 + nlo.
        // f16x4 store at p = wq*64 + nlo*4 + j  =>  n(p) as in header.
#pragma unroll
        for (int r = 0; r < 4; ++r) {
            const int nr = g * 16 + quad * 4 + r;
            f16x4 o;
#pragma unroll
            for (int j = 0; j < 4; ++j) o[j] = (_Float16)acc[j][r];
            *reinterpret_cast<f16x4*>(Y + (size_t)nr * 256 + wq * 64 +
                                      nlo * 4) = o;
        }

        // Convert next group's A (loads have had the whole MFMA block to
        // land); afn dies here, keeping only one f32 set live.
#pragma unroll
        for (int ks = 0; ks < 4; ++ks) {
            f16x8 t;
            t[0] = (_Float16)afn[ks][0].x; t[1] = (_Float16)afn[ks][0].y;
            t[2] = (_Float16)afn[ks][0].z; t[3] = (_Float16)afn[ks][0].w;
            t[4] = (_Float16)afn[ks][1].x; t[5] = (_Float16)afn[ks][1].y;
            t[6] = (_Float16)afn[ks][1].z; t[7] = (_Float16)afn[ks][1].w;
            av[ks] = t;
        }
    }
}

static __device__ __forceinline__ f16x2 pair2(const f16x8& v, int p) {
    f16x2 r; r[0] = v[2 * p]; r[1] = v[2 * p + 1]; return r;
}

// Edge phase: 16 lanes per edge (4 edges/wave/iter), coalesced 256-B segment
// gathers. Three-deep pipeline: gathers issued 2 iters ahead, indices 3.
__global__ __launch_bounds__(256, 8)
void edge_decode_kernel(const half_t* __restrict__ Y,
                        const int* __restrict__ es,
                        const int* __restrict__ ed,
                        const float* __restrict__ b1,
                        const float* __restrict__ W2,
                        const float* __restrict__ b2,
                        float* __restrict__ out,
                        int n_e, int stride_e) {
    __shared__ __align__(16) half_t b1h[128];
    __shared__ __align__(16) half_t w2h[128];
    if (threadIdx.x < 128) {
        const int i = threadIdx.x;
        // position i holds hidden index n(i) (per 128-half):
        const int n = (((i >> 6) << 2) + (i & 3)) * 16 + ((i >> 2) & 15);
        b1h[i] = (half_t)b1[n];
        w2h[i] = (half_t)W2[n];
    }
    __syncthreads();

    const int lane  = threadIdx.x & 63;
    const int sl    = lane & 15;    // 16-B slice within the 256-B half-row
    const int eslot = lane >> 4;    // which of the wave's 4 edges
    const f16x8 bv = reinterpret_cast<const f16x8*>(b1h)[sl];
    const f16x8 wv = reinterpret_cast<const f16x8*>(w2h)[sl];
    const float b2v = b2[0];
    const f16x2 zero2 = {(_Float16)0, (_Float16)0};

    const int w = blockIdx.x * 4 + (threadIdx.x >> 6);
    int e0 = w * 4;
    if (e0 >= n_e) return;

    // iter-0 gathers
    int ec = e0 + eslot; if (ec >= n_e) ec = 0;
    int sa = es[ec], da = ed[ec];
    f16x8 u0 = *reinterpret_cast<const f16x8*>(Y + (size_t)sa * 256 + sl * 8);
    f16x8 v0 = *reinterpret_cast<const f16x8*>(Y + (size_t)da * 256 + 128 +
                                               sl * 8);
    // iter-1 gathers
    ec = e0 + stride_e + eslot; if (ec >= n_e) ec = 0;
    sa = es[ec]; da = ed[ec];
    f16x8 u1 = *reinterpret_cast<const f16x8*>(Y + (size_t)sa * 256 + sl * 8);
    f16x8 v1 = *reinterpret_cast<const f16x8*>(Y + (size_t)da * 256 + 128 +
                                               sl * 8);
    // iter-2 indices
    ec = e0 + 2 * stride_e + eslot; if (ec >= n_e) ec = 0;
    int s2 = es[ec], d2 = ed[ec];

    for (; e0 < n_e; e0 += stride_e) {
        const int e = e0 + eslot;
        const bool valid = (e < n_e);

        // issue iter+2 gathers (consumed two iterations from now)
        const f16x8 u2 = *reinterpret_cast<const f16x8*>(
            Y + (size_t)s2 * 256 + sl * 8);
        const f16x8 v2 = *reinterpret_cast<const f16x8*>(
            Y + (size_t)d2 * 256 + 128 + sl * 8);

        // fetch indices three iterations ahead
        {
            int en = e0 + 3 * stride_e + eslot;
            if (en >= n_e) en = 0;
            s2 = es[en];
            d2 = ed[en];
        }

        float acc = 0.f;
#pragma unroll
        for (int p = 0; p < 4; ++p) {
            f16x2 h2 = pair2(u0, p) + pair2(v0, p) + pair2(bv, p);
            h2 = __builtin_elementwise_max(h2, zero2);
            acc = __builtin_amdgcn_fdot2(h2, pair2(wv, p), acc, false);
        }
        acc += __shfl_xor(acc, 1);
        acc += __shfl_xor(acc, 2);
        acc += __shfl_xor(acc, 4);
        acc += __shfl_xor(acc, 8);
        if (sl == 0 && valid) out[e] = acc + b2v;

        u0 = u1; v0 = v1;
        u1 = u2; v1 = v2;
    }
}

// Insurance fallback (only if workspace is unexpectedly tiny): correct, slow.
__global__ void naive_edge_kernel(const float* __restrict__ z,
                                  const int* __restrict__ eidx,
                                  const float* __restrict__ W1,
                                  const float* __restrict__ b1,
                                  const float* __restrict__ W2,
                                  const float* __restrict__ b2,
                                  float* __restrict__ out, int n_edges) {
    __shared__ float feat[256];
    __shared__ float red[2];
    const int e = blockIdx.x;
    const int t = threadIdx.x;           // 128 threads
    const int s = eidx[e], d = eidx[n_edges + e];
    feat[t] = z[(size_t)s * 128 + t];
    feat[128 + t] = z[(size_t)d * 128 + t];
    __syncthreads();
    float h = b1[t];
    for (int k = 0; k < 256; ++k) h = fmaf(feat[k], W1[k * 128 + t], h);
    float p = fmaxf(h, 0.f) * W2[t];
    for (int off = 32; off; off >>= 1) p += __shfl_down(p, off);
    if ((t & 63) == 0) red[t >> 6] = p;
    __syncthreads();
    if (t == 0) out[e] = red[0] + red[1] + b2[0];
}

extern "C" void kernel_launch(void* const* d_in, const int* in_sizes, int n_in,
                              void* d_out, int out_size, void* d_ws,
                              size_t ws_size, hipStream_t stream) {
    const float* z   = (const float*)d_in[0];
    const int* eidx  = (const int*)d_in[1];   // int64 ref passed as int32
    const float* W1  = (const float*)d_in[2];
    const float* b1  = (const float*)d_in[3];
    const float* W2  = (const float*)d_in[4];
    const float* b2  = (const float*)d_in[5];
    float* out       = (float*)d_out;

    const int nz      = in_sizes[0];          // 12,800,000
    const int n_nodes = nz / 128;             // 100,000
    const int n_edges = in_sizes[1] / 2;      // 1,000,000

    const size_t Y_bytes = (size_t)n_nodes * 256 * sizeof(half_t); // 51.2 MB

    if (ws_size >= Y_bytes) {
        half_t* Y = (half_t*)d_ws;

        const int n_groups = n_nodes / 16;          // 6250 exact
        const int gblocks  = 768;                   // 3 blocks/CU residency
        gemm_fused_kernel<<<gblocks, 256, 0, stream>>>(z, W1, Y, n_groups,
                                                       gblocks);

        const int eblocks  = 2048;                  // 8 blocks/CU -> 32 w/CU
        const int stride_e = eblocks * 4 * 4;       // 32768
        edge_decode_kernel<<<eblocks, 256, 0, stream>>>(
            Y, eidx, eidx + n_edges, b1, W2, b2, out, n_edges, stride_e);
    } else {
        naive_edge_kernel<<<n_edges, 128, 0, stream>>>(z, eidx, W1, b1, W2, b2,
                                                       out, n_edges);
    }
}

// Round 5
// 178.643 us; speedup vs baseline: 1.2461x; 1.0897x over previous
//
#include <hip/hip_runtime.h>
#include <hip/hip_fp16.h>

typedef _Float16 half_t;
typedef __attribute__((ext_vector_type(2))) _Float16 f16x2;
typedef __attribute__((ext_vector_type(4))) _Float16 f16x4;
typedef __attribute__((ext_vector_type(8))) _Float16 f16x8;
typedef __attribute__((ext_vector_type(4))) float f32x4;

// ---------------------------------------------------------------------------
// Separable MLP: h = relu(z[src].W1a + z[dst].W1b + b1) ; out = h.W2 + b2
// R5: gemm = LDS-A hybrid. Accounting showed R4's in-wave fused cvt made gemm
//   ~46 us (vs ~27 regb): the 4x per-wave A redundancy in f32 was structural.
//   New gemm_all: block stages each group's A-tile (4 KB f16) in LDS ONCE
//   (converted from z f32 by all 256 threads), double-buffered (8 KB), one
//   barrier/iter; B stays register-resident per wave (R3-proven), loaded from
//   w1s blob built by a 128-block micro-prep (~2 us). z read once, no zh
//   round-trip: traffic floor ~103 MB ~ 16 us.
//   LDS A swizzle: slot ^= (row&7) -> both ds_write_b128 and frag
//   ds_read_b128 hit the uniform 8-lane/4-bank-group minimum (16-way
//   conflict without it).
// Phase 2 (edge_decode): out[e] = b2 + relu(Y[s][0:128]+Y[d][128:256]+b1).W2
//   16 lanes/edge, 2048 blocks, 3-deep pipeline (R0 config; R1's 4-deep+nt
//   regressed: contention/fabric-bound at ~240 MB L2-miss, 73.4 us).
// Y row layout (256 f16): position p holds hidden index
//   n(p) = ((p>>6)*4 + (p&3))*16 + ((p>>2)&15) per 128-half; b1/W2 permuted
//   identically in edge (edge math positional; any bijection works).
// Fixed harness overhead (fillBuffer re-poison): ~75 us/replay, not ours.
// ---------------------------------------------------------------------------

// Micro-prep: W1 -> f16 B-fragment blob (64 KB), 128 blocks.
// B-fragment (ks 0..3, nt 0..15): lane L elem j holds
//   B[k = ks*32 + (L>>4)*8 + j][ncol = nt*16 + (L&15)]
// where B[k][ncol] = W1[(ncol<128 ? k : 128+k)][ncol & 127].
// Flat f16 index t = ((ks*16 + nt)*64 + L)*8 + j.
__global__ void prep_w1_kernel(const float* __restrict__ W1,
                               half_t* __restrict__ w1s) {
    const int t = blockIdx.x * 256 + threadIdx.x;   // 0..32767
    const int j  = t & 7;
    const int L  = (t >> 3) & 63;
    const int nt = (t >> 9) & 15;
    const int ks = t >> 13;
    const int k    = ks * 32 + (L >> 4) * 8 + j;
    const int ncol = nt * 16 + (L & 15);
    const int row  = (ncol < 128) ? k : 128 + k;
    w1s[t] = (half_t)W1[row * 128 + (ncol & 127)];
}

// Fused gemm: Y[node] = [z@W1a | z@W1b] in f16, A staged through LDS.
// Block = 4 waves; wave wq owns 64 output cols (B quarter in 64 VGPRs from
// w1s blob). Per iter: all 256 threads cvt-stage next A-tile (2 float4 loads
// + ds_write_b128), each wave ds_reads its 4 A-frags + 16 MFMA + 4 f16x4
// stores. One barrier per iter (write target = buffer read LAST iter).
// LDS layout (per 4KB buf): elem(r, c) at f16 index
//   r*128 + ((c/8) ^ (r&7))*8 + (c&7),  r=0..15, c=0..127.
__global__ __launch_bounds__(256, 3)
void gemm_all_kernel(const float* __restrict__ z,
                     const half_t* __restrict__ w1s,
                     half_t* __restrict__ Y,
                     int n_groups, int stride_groups) {
    __shared__ __align__(16) half_t abuf[2][2048];   // 2 x 4 KB

    const int tid  = threadIdx.x;
    const int wq   = tid >> 6;           // wave's column-quarter, 0..3
    const int lane = tid & 63;
    const int nlo  = lane & 15;
    const int quad = lane >> 4;

    // B quarter in registers (16 KB/wave) from prebuilt blob (R3-proven).
    const f16x8* blob = reinterpret_cast<const f16x8*>(w1s);
    f16x8 breg[4][4];                    // [ks][ntp]
#pragma unroll
    for (int ks = 0; ks < 4; ++ks)
#pragma unroll
        for (int ntp = 0; ntp < 4; ++ntp)
            breg[ks][ntp] = blob[(ks * 16 + wq * 4 + ntp) * 64 + lane];

    // Staging role for this thread: row sr (0..15), slot sslot (0..15).
    const int sr    = tid & 15;
    const int sslot = tid >> 4;
    const int swz_w = (sslot ^ (sr & 7)) * 8 + sr * 128;  // f16 idx in buf
    // Frag-read offsets: row nlo, slots quad + 4*ks.
    // f16 idx = nlo*128 + ((quad + 4*ks) ^ (nlo&7))*8.

    int g = blockIdx.x;                  // grid = 768 <= n_groups always

    // Prologue: stage A[g] into buf0.
    {
        const float4* ap = reinterpret_cast<const float4*>(
            z + ((size_t)(g * 16 + sr) * 128) + sslot * 8);
        const float4 a0 = ap[0];
        const float4 a1 = ap[1];
        f16x8 w;
        w[0] = (_Float16)a0.x; w[1] = (_Float16)a0.y;
        w[2] = (_Float16)a0.z; w[3] = (_Float16)a0.w;
        w[4] = (_Float16)a1.x; w[5] = (_Float16)a1.y;
        w[6] = (_Float16)a1.z; w[7] = (_Float16)a1.w;
        *reinterpret_cast<f16x8*>(&abuf[0][swz_w]) = w;
    }
    __syncthreads();

    int cur = 0;
    for (; g < n_groups; g += stride_groups) {
        // Issue next tile's global loads early (full MFMA block of slack).
        const int gn  = g + stride_groups;
        const int gpi = (gn < n_groups) ? gn : g;   // harmless re-read on last
        const float4* apn = reinterpret_cast<const float4*>(
            z + ((size_t)(gpi * 16 + sr) * 128) + sslot * 8);
        const float4 a0 = apn[0];
        const float4 a1 = apn[1];

        // A fragments from LDS (swizzled, uniform bank spread).
        f16x8 av[4];
#pragma unroll
        for (int ks = 0; ks < 4; ++ks)
            av[ks] = *reinterpret_cast<const f16x8*>(
                &abuf[cur][nlo * 128 + (((quad + 4 * ks) ^ (nlo & 7)) << 3)]);

        f32x4 acc[4];
#pragma unroll
        for (int ntp = 0; ntp < 4; ++ntp)
            acc[ntp] = (f32x4){0.f, 0.f, 0.f, 0.f};

#pragma unroll
        for (int ks = 0; ks < 4; ++ks)
#pragma unroll
            for (int ntp = 0; ntp < 4; ++ntp)
                acc[ntp] = __builtin_amdgcn_mfma_f32_16x16x32_f16(
                    av[ks], breg[ks][ntp], acc[ntp], 0, 0, 0);

        // C/D: row m = quad*4 + r, col = (wq*4+ntp)*16 + nlo.
        // f16x4 store at p = wq*64 + nlo*4 + j  =>  n(p) as in header.
#pragma unroll
        for (int r = 0; r < 4; ++r) {
            const int nr = g * 16 + quad * 4 + r;
            f16x4 o;
#pragma unroll
            for (int j = 0; j < 4; ++j) o[j] = (_Float16)acc[j][r];
            *reinterpret_cast<f16x4*>(Y + (size_t)nr * 256 + wq * 64 +
                                      nlo * 4) = o;
        }

        // Convert + stage next tile into the other buffer.
        {
            f16x8 w;
            w[0] = (_Float16)a0.x; w[1] = (_Float16)a0.y;
            w[2] = (_Float16)a0.z; w[3] = (_Float16)a0.w;
            w[4] = (_Float16)a1.x; w[5] = (_Float16)a1.y;
            w[6] = (_Float16)a1.z; w[7] = (_Float16)a1.w;
            *reinterpret_cast<f16x8*>(&abuf[cur ^ 1][swz_w]) = w;
        }
        __syncthreads();   // separates this write from next iter's reads AND
                           // this iter's reads from next iter's write.
        cur ^= 1;
    }
}

static __device__ __forceinline__ f16x2 pair2(const f16x8& v, int p) {
    f16x2 r; r[0] = v[2 * p]; r[1] = v[2 * p + 1]; return r;
}

// Edge phase: 16 lanes per edge (4 edges/wave/iter), coalesced 256-B segment
// gathers. Three-deep pipeline: gathers issued 2 iters ahead, indices 3.
__global__ __launch_bounds__(256, 8)
void edge_decode_kernel(const half_t* __restrict__ Y,
                        const int* __restrict__ es,
                        const int* __restrict__ ed,
                        const float* __restrict__ b1,
                        const float* __restrict__ W2,
                        const float* __restrict__ b2,
                        float* __restrict__ out,
                        int n_e, int stride_e) {
    __shared__ __align__(16) half_t b1h[128];
    __shared__ __align__(16) half_t w2h[128];
    if (threadIdx.x < 128) {
        const int i = threadIdx.x;
        // position i holds hidden index n(i) (per 128-half):
        const int n = (((i >> 6) << 2) + (i & 3)) * 16 + ((i >> 2) & 15);
        b1h[i] = (half_t)b1[n];
        w2h[i] = (half_t)W2[n];
    }
    __syncthreads();

    const int lane  = threadIdx.x & 63;
    const int sl    = lane & 15;    // 16-B slice within the 256-B half-row
    const int eslot = lane >> 4;    // which of the wave's 4 edges
    const f16x8 bv = reinterpret_cast<const f16x8*>(b1h)[sl];
    const f16x8 wv = reinterpret_cast<const f16x8*>(w2h)[sl];
    const float b2v = b2[0];
    const f16x2 zero2 = {(_Float16)0, (_Float16)0};

    const int w = blockIdx.x * 4 + (threadIdx.x >> 6);
    int e0 = w * 4;
    if (e0 >= n_e) return;

    // iter-0 gathers
    int ec = e0 + eslot; if (ec >= n_e) ec = 0;
    int sa = es[ec], da = ed[ec];
    f16x8 u0 = *reinterpret_cast<const f16x8*>(Y + (size_t)sa * 256 + sl * 8);
    f16x8 v0 = *reinterpret_cast<const f16x8*>(Y + (size_t)da * 256 + 128 +
                                               sl * 8);
    // iter-1 gathers
    ec = e0 + stride_e + eslot; if (ec >= n_e) ec = 0;
    sa = es[ec]; da = ed[ec];
    f16x8 u1 = *reinterpret_cast<const f16x8*>(Y + (size_t)sa * 256 + sl * 8);
    f16x8 v1 = *reinterpret_cast<const f16x8*>(Y + (size_t)da * 256 + 128 +
                                               sl * 8);
    // iter-2 indices
    ec = e0 + 2 * stride_e + eslot; if (ec >= n_e) ec = 0;
    int s2 = es[ec], d2 = ed[ec];

    for (; e0 < n_e; e0 += stride_e) {
        const int e = e0 + eslot;
        const bool valid = (e < n_e);

        // issue iter+2 gathers (consumed two iterations from now)
        const f16x8 u2 = *reinterpret_cast<const f16x8*>(
            Y + (size_t)s2 * 256 + sl * 8);
        const f16x8 v2 = *reinterpret_cast<const f16x8*>(
            Y + (size_t)d2 * 256 + 128 + sl * 8);

        // fetch indices three iterations ahead
        {
            int en = e0 + 3 * stride_e + eslot;
            if (en >= n_e) en = 0;
            s2 = es[en];
            d2 = ed[en];
        }

        float acc = 0.f;
#pragma unroll
        for (int p = 0; p < 4; ++p) {
            f16x2 h2 = pair2(u0, p) + pair2(v0, p) + pair2(bv, p);
            h2 = __builtin_elementwise_max(h2, zero2);
            acc = __builtin_amdgcn_fdot2(h2, pair2(wv, p), acc, false);
        }
        acc += __shfl_xor(acc, 1);
        acc += __shfl_xor(acc, 2);
        acc += __shfl_xor(acc, 4);
        acc += __shfl_xor(acc, 8);
        if (sl == 0 && valid) out[e] = acc + b2v;

        u0 = u1; v0 = v1;
        u1 = u2; v1 = v2;
    }
}

// Insurance fallback (only if workspace is unexpectedly tiny): correct, slow.
__global__ void naive_edge_kernel(const float* __restrict__ z,
                                  const int* __restrict__ eidx,
                                  const float* __restrict__ W1,
                                  const float* __restrict__ b1,
                                  const float* __restrict__ W2,
                                  const float* __restrict__ b2,
                                  float* __restrict__ out, int n_edges) {
    __shared__ float feat[256];
    __shared__ float red[2];
    const int e = blockIdx.x;
    const int t = threadIdx.x;           // 128 threads
    const int s = eidx[e], d = eidx[n_edges + e];
    feat[t] = z[(size_t)s * 128 + t];
    feat[128 + t] = z[(size_t)d * 128 + t];
    __syncthreads();
    float h = b1[t];
    for (int k = 0; k < 256; ++k) h = fmaf(feat[k], W1[k * 128 + t], h);
    float p = fmaxf(h, 0.f) * W2[t];
    for (int off = 32; off; off >>= 1) p += __shfl_down(p, off);
    if ((t & 63) == 0) red[t >> 6] = p;
    __syncthreads();
    if (t == 0) out[e] = red[0] + red[1] + b2[0];
}

extern "C" void kernel_launch(void* const* d_in, const int* in_sizes, int n_in,
                              void* d_out, int out_size, void* d_ws,
                              size_t ws_size, hipStream_t stream) {
    const float* z   = (const float*)d_in[0];
    const int* eidx  = (const int*)d_in[1];   // int64 ref passed as int32
    const float* W1  = (const float*)d_in[2];
    const float* b1  = (const float*)d_in[3];
    const float* W2  = (const float*)d_in[4];
    const float* b2  = (const float*)d_in[5];
    float* out       = (float*)d_out;

    const int nz      = in_sizes[0];          // 12,800,000
    const int n_nodes = nz / 128;             // 100,000
    const int n_edges = in_sizes[1] / 2;      // 1,000,000

    const size_t Y_bytes   = (size_t)n_nodes * 256 * sizeof(half_t); // 51.2 MB
    const size_t w1s_bytes = 32768 * sizeof(half_t);                 // 64 KB

    if (ws_size >= Y_bytes + w1s_bytes) {
        half_t* Y   = (half_t*)d_ws;
        half_t* w1s = (half_t*)((char*)d_ws + Y_bytes);

        prep_w1_kernel<<<128, 256, 0, stream>>>(W1, w1s);

        const int n_groups = n_nodes / 16;          // 6250 exact
        const int gblocks  = 768;                   // 3 blocks/CU residency
        gemm_all_kernel<<<gblocks, 256, 0, stream>>>(z, w1s, Y, n_groups,
                                                     gblocks);

        const int eblocks  = 2048;                  // 8 blocks/CU -> 32 w/CU
        const int stride_e = eblocks * 4 * 4;       // 32768
        edge_decode_kernel<<<eblocks, 256, 0, stream>>>(
            Y, eidx, eidx + n_edges, b1, W2, b2, out, n_edges, stride_e);
    } else {
        naive_edge_kernel<<<n_edges, 128, 0, stream>>>(z, eidx, W1, b1, W2, b2,
                                                       out, n_edges);
    }
}

// Round 6
// 176.416 us; speedup vs baseline: 1.2618x; 1.0126x over previous
//
#include <hip/hip_runtime.h>
#include <hip/hip_fp16.h>

typedef _Float16 half_t;
typedef __attribute__((ext_vector_type(2))) _Float16 f16x2;
typedef __attribute__((ext_vector_type(4))) _Float16 f16x4;
typedef __attribute__((ext_vector_type(8))) _Float16 f16x8;
typedef __attribute__((ext_vector_type(4))) float f32x4;

// ---------------------------------------------------------------------------
// Separable MLP: h = relu(z[src].W1a + z[dst].W1b + b1) ; out = h.W2 + b2
// R6: fix gemm z-read coalescing. R5's LDS-A hybrid gemm landed ~26 us vs a
//   15.9 us traffic floor (100 MB @ 6.3 TB/s). Root cause found in staging
//   address math: sr=tid&15 made each wave's float4 loads a 512-B-strided
//   16-line scatter (16 B used per line per instr). Swap to sr=tid>>4,
//   sslot=tid&15: wave reads 4 contiguous 1-KB row segments (~4x fewer line
//   requests, same bytes). Work set per block unchanged -> LDS layout
//   contract, swizzle, cvt, MFMA all bit-identical.
// Edge phase FROZEN: counters rigid across R0/R4/R5 (73.4 us, 239.6 MB,
//   3.4 TB/s ~ 52% of stream rate = random-access fabric ceiling; R1 showed
//   deeper pipelining/nt both hurt). Remaining edge ideas (2D bucket sort,
//   fp8 Y) are net-negative or precision-risky by arithmetic.
// Fixed harness overhead (fillBuffer re-poison): ~75 us/replay, not ours.
// Structure: prep_w1 (2 us) -> gemm_all (LDS-A dbuf + register-B) -> edge.
// Y row layout (256 f16): position p holds hidden index
//   n(p) = ((p>>6)*4 + (p&3))*16 + ((p>>2)&15) per 128-half; b1/W2 permuted
//   identically in edge (edge math positional; any bijection works).
// ---------------------------------------------------------------------------

// Micro-prep: W1 -> f16 B-fragment blob (64 KB), 128 blocks.
// B-fragment (ks 0..3, nt 0..15): lane L elem j holds
//   B[k = ks*32 + (L>>4)*8 + j][ncol = nt*16 + (L&15)]
// where B[k][ncol] = W1[(ncol<128 ? k : 128+k)][ncol & 127].
// Flat f16 index t = ((ks*16 + nt)*64 + L)*8 + j.
__global__ void prep_w1_kernel(const float* __restrict__ W1,
                               half_t* __restrict__ w1s) {
    const int t = blockIdx.x * 256 + threadIdx.x;   // 0..32767
    const int j  = t & 7;
    const int L  = (t >> 3) & 63;
    const int nt = (t >> 9) & 15;
    const int ks = t >> 13;
    const int k    = ks * 32 + (L >> 4) * 8 + j;
    const int ncol = nt * 16 + (L & 15);
    const int row  = (ncol < 128) ? k : 128 + k;
    w1s[t] = (half_t)W1[row * 128 + (ncol & 127)];
}

// Fused gemm: Y[node] = [z@W1a | z@W1b] in f16, A staged through LDS.
// Block = 4 waves; wave wq owns 64 output cols (B quarter in 64 VGPRs from
// w1s blob). Per iter: all 256 threads cvt-stage next A-tile (2 float4 loads
// + ds_write_b128), each wave ds_reads its 4 A-frags + 16 MFMA + 4 f16x4
// stores. One barrier per iter (write target = buffer read LAST iter).
// LDS layout (per 4KB buf): elem(r, c) at f16 index
//   r*128 + ((c/8) ^ (r&7))*8 + (c&7),  r=0..15, c=0..127.
__global__ __launch_bounds__(256, 3)
void gemm_all_kernel(const float* __restrict__ z,
                     const half_t* __restrict__ w1s,
                     half_t* __restrict__ Y,
                     int n_groups, int stride_groups) {
    __shared__ __align__(16) half_t abuf[2][2048];   // 2 x 4 KB

    const int tid  = threadIdx.x;
    const int wq   = tid >> 6;           // wave's column-quarter, 0..3
    const int lane = tid & 63;
    const int nlo  = lane & 15;
    const int quad = lane >> 4;

    // B quarter in registers (16 KB/wave) from prebuilt blob (R3-proven).
    const f16x8* blob = reinterpret_cast<const f16x8*>(w1s);
    f16x8 breg[4][4];                    // [ks][ntp]
#pragma unroll
    for (int ks = 0; ks < 4; ++ks)
#pragma unroll
        for (int ntp = 0; ntp < 4; ++ntp)
            breg[ks][ntp] = blob[(ks * 16 + wq * 4 + ntp) * 64 + lane];

    // Staging role: row sr (0..15), col-chunk sslot (0..15).
    // R6: sr = tid>>4 (was tid&15) -> a wave covers 4 CONTIGUOUS rows
    // (4 x 1 KB dense segments) instead of a 512-B-strided 16-line scatter.
    const int sr    = tid >> 4;
    const int sslot = tid & 15;
    const int swz_w = (sslot ^ (sr & 7)) * 8 + sr * 128;  // f16 idx in buf
    // Frag-read offsets: row nlo, slots quad + 4*ks.
    // f16 idx = nlo*128 + ((quad + 4*ks) ^ (nlo&7))*8.

    int g = blockIdx.x;                  // grid = 768 <= n_groups always

    // Prologue: stage A[g] into buf0.
    {
        const float4* ap = reinterpret_cast<const float4*>(
            z + ((size_t)(g * 16 + sr) * 128) + sslot * 8);
        const float4 a0 = ap[0];
        const float4 a1 = ap[1];
        f16x8 w;
        w[0] = (_Float16)a0.x; w[1] = (_Float16)a0.y;
        w[2] = (_Float16)a0.z; w[3] = (_Float16)a0.w;
        w[4] = (_Float16)a1.x; w[5] = (_Float16)a1.y;
        w[6] = (_Float16)a1.z; w[7] = (_Float16)a1.w;
        *reinterpret_cast<f16x8*>(&abuf[0][swz_w]) = w;
    }
    __syncthreads();

    int cur = 0;
    for (; g < n_groups; g += stride_groups) {
        // Issue next tile's global loads early (full MFMA block of slack).
        const int gn  = g + stride_groups;
        const int gpi = (gn < n_groups) ? gn : g;   // harmless re-read on last
        const float4* apn = reinterpret_cast<const float4*>(
            z + ((size_t)(gpi * 16 + sr) * 128) + sslot * 8);
        const float4 a0 = apn[0];
        const float4 a1 = apn[1];

        // A fragments from LDS (swizzled, uniform bank spread).
        f16x8 av[4];
#pragma unroll
        for (int ks = 0; ks < 4; ++ks)
            av[ks] = *reinterpret_cast<const f16x8*>(
                &abuf[cur][nlo * 128 + (((quad + 4 * ks) ^ (nlo & 7)) << 3)]);

        f32x4 acc[4];
#pragma unroll
        for (int ntp = 0; ntp < 4; ++ntp)
            acc[ntp] = (f32x4){0.f, 0.f, 0.f, 0.f};

#pragma unroll
        for (int ks = 0; ks < 4; ++ks)
#pragma unroll
            for (int ntp = 0; ntp < 4; ++ntp)
                acc[ntp] = __builtin_amdgcn_mfma_f32_16x16x32_f16(
                    av[ks], breg[ks][ntp], acc[ntp], 0, 0, 0);

        // C/D: row m = quad*4 + r, col = (wq*4+ntp)*16 + nlo.
        // f16x4 store at p = wq*64 + nlo*4 + j  =>  n(p) as in header.
#pragma unroll
        for (int r = 0; r < 4; ++r) {
            const int nr = g * 16 + quad * 4 + r;
            f16x4 o;
#pragma unroll
            for (int j = 0; j < 4; ++j) o[j] = (_Float16)acc[j][r];
            *reinterpret_cast<f16x4*>(Y + (size_t)nr * 256 + wq * 64 +
                                      nlo * 4) = o;
        }

        // Convert + stage next tile into the other buffer.
        {
            f16x8 w;
            w[0] = (_Float16)a0.x; w[1] = (_Float16)a0.y;
            w[2] = (_Float16)a0.z; w[3] = (_Float16)a0.w;
            w[4] = (_Float16)a1.x; w[5] = (_Float16)a1.y;
            w[6] = (_Float16)a1.z; w[7] = (_Float16)a1.w;
            *reinterpret_cast<f16x8*>(&abuf[cur ^ 1][swz_w]) = w;
        }
        __syncthreads();   // separates this write from next iter's reads AND
                           // this iter's reads from next iter's write.
        cur ^= 1;
    }
}

static __device__ __forceinline__ f16x2 pair2(const f16x8& v, int p) {
    f16x2 r; r[0] = v[2 * p]; r[1] = v[2 * p + 1]; return r;
}

// Edge phase: 16 lanes per edge (4 edges/wave/iter), coalesced 256-B segment
// gathers. Three-deep pipeline: gathers issued 2 iters ahead, indices 3.
// FROZEN at R0 config (fabric-bound; R1 probes regressed).
__global__ __launch_bounds__(256, 8)
void edge_decode_kernel(const half_t* __restrict__ Y,
                        const int* __restrict__ es,
                        const int* __restrict__ ed,
                        const float* __restrict__ b1,
                        const float* __restrict__ W2,
                        const float* __restrict__ b2,
                        float* __restrict__ out,
                        int n_e, int stride_e) {
    __shared__ __align__(16) half_t b1h[128];
    __shared__ __align__(16) half_t w2h[128];
    if (threadIdx.x < 128) {
        const int i = threadIdx.x;
        // position i holds hidden index n(i) (per 128-half):
        const int n = (((i >> 6) << 2) + (i & 3)) * 16 + ((i >> 2) & 15);
        b1h[i] = (half_t)b1[n];
        w2h[i] = (half_t)W2[n];
    }
    __syncthreads();

    const int lane  = threadIdx.x & 63;
    const int sl    = lane & 15;    // 16-B slice within the 256-B half-row
    const int eslot = lane >> 4;    // which of the wave's 4 edges
    const f16x8 bv = reinterpret_cast<const f16x8*>(b1h)[sl];
    const f16x8 wv = reinterpret_cast<const f16x8*>(w2h)[sl];
    const float b2v = b2[0];
    const f16x2 zero2 = {(_Float16)0, (_Float16)0};

    const int w = blockIdx.x * 4 + (threadIdx.x >> 6);
    int e0 = w * 4;
    if (e0 >= n_e) return;

    // iter-0 gathers
    int ec = e0 + eslot; if (ec >= n_e) ec = 0;
    int sa = es[ec], da = ed[ec];
    f16x8 u0 = *reinterpret_cast<const f16x8*>(Y + (size_t)sa * 256 + sl * 8);
    f16x8 v0 = *reinterpret_cast<const f16x8*>(Y + (size_t)da * 256 + 128 +
                                               sl * 8);
    // iter-1 gathers
    ec = e0 + stride_e + eslot; if (ec >= n_e) ec = 0;
    sa = es[ec]; da = ed[ec];
    f16x8 u1 = *reinterpret_cast<const f16x8*>(Y + (size_t)sa * 256 + sl * 8);
    f16x8 v1 = *reinterpret_cast<const f16x8*>(Y + (size_t)da * 256 + 128 +
                                               sl * 8);
    // iter-2 indices
    ec = e0 + 2 * stride_e + eslot; if (ec >= n_e) ec = 0;
    int s2 = es[ec], d2 = ed[ec];

    for (; e0 < n_e; e0 += stride_e) {
        const int e = e0 + eslot;
        const bool valid = (e < n_e);

        // issue iter+2 gathers (consumed two iterations from now)
        const f16x8 u2 = *reinterpret_cast<const f16x8*>(
            Y + (size_t)s2 * 256 + sl * 8);
        const f16x8 v2 = *reinterpret_cast<const f16x8*>(
            Y + (size_t)d2 * 256 + 128 + sl * 8);

        // fetch indices three iterations ahead
        {
            int en = e0 + 3 * stride_e + eslot;
            if (en >= n_e) en = 0;
            s2 = es[en];
            d2 = ed[en];
        }

        float acc = 0.f;
#pragma unroll
        for (int p = 0; p < 4; ++p) {
            f16x2 h2 = pair2(u0, p) + pair2(v0, p) + pair2(bv, p);
            h2 = __builtin_elementwise_max(h2, zero2);
            acc = __builtin_amdgcn_fdot2(h2, pair2(wv, p), acc, false);
        }
        acc += __shfl_xor(acc, 1);
        acc += __shfl_xor(acc, 2);
        acc += __shfl_xor(acc, 4);
        acc += __shfl_xor(acc, 8);
        if (sl == 0 && valid) out[e] = acc + b2v;

        u0 = u1; v0 = v1;
        u1 = u2; v1 = v2;
    }
}

// Insurance fallback (only if workspace is unexpectedly tiny): correct, slow.
__global__ void naive_edge_kernel(const float* __restrict__ z,
                                  const int* __restrict__ eidx,
                                  const float* __restrict__ W1,
                                  const float* __restrict__ b1,
                                  const float* __restrict__ W2,
                                  const float* __restrict__ b2,
                                  float* __restrict__ out, int n_edges) {
    __shared__ float feat[256];
    __shared__ float red[2];
    const int e = blockIdx.x;
    const int t = threadIdx.x;           // 128 threads
    const int s = eidx[e], d = eidx[n_edges + e];
    feat[t] = z[(size_t)s * 128 + t];
    feat[128 + t] = z[(size_t)d * 128 + t];
    __syncthreads();
    float h = b1[t];
    for (int k = 0; k < 256; ++k) h = fmaf(feat[k], W1[k * 128 + t], h);
    float p = fmaxf(h, 0.f) * W2[t];
    for (int off = 32; off; off >>= 1) p += __shfl_down(p, off);
    if ((t & 63) == 0) red[t >> 6] = p;
    __syncthreads();
    if (t == 0) out[e] = red[0] + red[1] + b2[0];
}

extern "C" void kernel_launch(void* const* d_in, const int* in_sizes, int n_in,
                              void* d_out, int out_size, void* d_ws,
                              size_t ws_size, hipStream_t stream) {
    const float* z   = (const float*)d_in[0];
    const int* eidx  = (const int*)d_in[1];   // int64 ref passed as int32
    const float* W1  = (const float*)d_in[2];
    const float* b1  = (const float*)d_in[3];
    const float* W2  = (const float*)d_in[4];
    const float* b2  = (const float*)d_in[5];
    float* out       = (float*)d_out;

    const int nz      = in_sizes[0];          // 12,800,000
    const int n_nodes = nz / 128;             // 100,000
    const int n_edges = in_sizes[1] / 2;      // 1,000,000

    const size_t Y_bytes   = (size_t)n_nodes * 256 * sizeof(half_t); // 51.2 MB
    const size_t w1s_bytes = 32768 * sizeof(half_t);                 // 64 KB

    if (ws_size >= Y_bytes + w1s_bytes) {
        half_t* Y   = (half_t*)d_ws;
        half_t* w1s = (half_t*)((char*)d_ws + Y_bytes);

        prep_w1_kernel<<<128, 256, 0, stream>>>(W1, w1s);

        const int n_groups = n_nodes / 16;          // 6250 exact
        const int gblocks  = 768;                   // 3 blocks/CU residency
        gemm_all_kernel<<<gblocks, 256, 0, stream>>>(z, w1s, Y, n_groups,
                                                     gblocks);

        const int eblocks  = 2048;                  // 8 blocks/CU -> 32 w/CU
        const int stride_e = eblocks * 4 * 4;       // 32768
        edge_decode_kernel<<<eblocks, 256, 0, stream>>>(
            Y, eidx, eidx + n_edges, b1, W2, b2, out, n_edges, stride_e);
    } else {
        naive_edge_kernel<<<n_edges, 128, 0, stream>>>(z, eidx, W1, b1, W2, b2,
                                                       out, n_edges);
    }
}